// Round 2
// baseline (128.130 us; speedup 1.0000x reference)
//
#include <hip/hip_runtime.h>
#include <hip/hip_fp16.h>

// Trilinear 3D-LUT interpolation (image-adaptive-3DLUT forward).
// lut: [3, 33, 33, 33] fp32, x: [4, 3, 1024, 1024] fp32 in [0,1], out same as x.
//
// R5: merged single-pass. R4 showed the 256 MiB ws poison fill is
// unconditional and wipes L2/L3 right before our kernel; the 3-channel-block
// structure read x 3x from HBM if XCD-L2 sharing missed, across 3 block
// generations. Changes:
//  - grid = 256 (one block per chunk, 1 block/CU, ONE generation). Each block
//    reads its x chunk ONCE (50.3 MB total HBM instead of up to 151 MB),
//    precomputes cell indices + deltas into registers, then processes all 3
//    channels serially.
//  - per channel: in-kernel pack of the fp32 LUT channel into fp16-pair u32s
//    in LDS (W[i] = (half(v[i]), half(v[i+1]))), barrier, gather. fp16 pairs
//    give 2 ds_read2_b32 per pixel (4 corners each) -> half the LDS-pipe work
//    of fp32 pairs. absmax 0.00195 with this representation passed in R3.
//  - no workspace, no pack kernel, single dispatch.

#define LUT_D      33
#define LUT_DD     (LUT_D * LUT_D)            // 1089
#define LUT_N      (LUT_D * LUT_D * LUT_D)    // 35937
#define HW4        (1024 * 1024 / 4)          // 262144 float4 groups per plane
#define NGROUPS    (4 * HW4)                  // 1048576 float4 groups per plane-set
#define NCHUNKS    256
#define THREADS    1024
#define ITERS      (NGROUPS / NCHUNKS / THREADS)       // 4
#define PACK_ROUNDS ((LUT_N + THREADS - 1) / THREADS)  // 36

typedef float vfloat4 __attribute__((ext_vector_type(4)));

__device__ __forceinline__ unsigned int pack2(float a, float b) {
    union { __half2 h; unsigned int u; } cv;
    cv.h = __floats2half2_rn(a, b);
    return cv.u;
}
__device__ __forceinline__ float2 unpack2(unsigned int p) {
    union { unsigned int u; __half2 h; } cv;
    cv.u = p;
    return __half22float2(cv.h);
}

__global__ __launch_bounds__(THREADS)
void lut3d_trilerp_kernel(const float* __restrict__ lut,
                          const float* __restrict__ x,
                          float* __restrict__ out) {
    extern __shared__ __align__(16) unsigned int W[];  // LUT_N u32 = 143,748 B

    const int t     = (int)threadIdx.x;
    const int chunk = blockIdx.x;                      // [0, 256)

    const float4* x4 = (const float4*)x;
    float4*       o4 = (float4*)out;
    const int g0 = chunk * (NGROUPS / NCHUNKS) + t;

    // ---- Phase A: read x chunk ONCE, derive indices + deltas, drop x.
    int   ibase[ITERS];
    int   idx[ITERS][4];
    float dr[ITERS][4], dg[ITERS][4], db[ITERS][4];
#pragma unroll
    for (int it = 0; it < ITERS; ++it) {
        const int g     = g0 + it * THREADS;
        const int b_img = g >> 18;            // g / HW4  (HW4 = 2^18)
        const int hw4   = g & (HW4 - 1);
        ibase[it] = b_img * 3 * HW4 + hw4;
        const float4 R = x4[ibase[it]];
        const float4 G = x4[ibase[it] + HW4];
        const float4 B = x4[ibase[it] + 2 * HW4];
        const float rr[4] = {R.x, R.y, R.z, R.w};
        const float gg[4] = {G.x, G.y, G.z, G.w};
        const float bb[4] = {B.x, B.y, B.z, B.w};
#pragma unroll
        for (int k = 0; k < 4; ++k) {
            const float sr = rr[k] * 32.0f;
            const float sg = gg[k] * 32.0f;
            const float sb = bb[k] * 32.0f;
            const float fr = fminf(fmaxf(floorf(sr), 0.0f), 31.0f);
            const float fg = fminf(fmaxf(floorf(sg), 0.0f), 31.0f);
            const float fb = fminf(fmaxf(floorf(sb), 0.0f), 31.0f);
            dr[it][k] = sr - fr;
            dg[it][k] = sg - fg;
            db[it][k] = sb - fb;
            idx[it][k] = ((int)fb * LUT_D + (int)fg) * LUT_D + (int)fr;
        }
    }

    // ---- Phase B: channels serially, re-packing LDS per channel.
    for (int c = 0; c < 3; ++c) {
        if (c) __syncthreads();   // previous channel's gathers done before overwrite

        // Pack fp32 channel -> fp16-pair u32 in LDS. Lanes write dword i at
        // bank i%32 == t%32 -> conflict-free; global loads coalesced per round.
        const float* Lc = lut + c * LUT_N;
#pragma unroll 4
        for (int r = 0; r < PACK_ROUNDS; ++r) {
            const int i = r * THREADS + t;
            if (i < LUT_N) {
                const float a = Lc[i];
                const float b = (i + 1 < LUT_N) ? Lc[i + 1] : 0.0f;
                W[i] = pack2(a, b);
            }
        }
        __syncthreads();

#pragma unroll
        for (int it = 0; it < ITERS; ++it) {
            // 8 corners per pixel as 4 fp16-pairs -> 2 ds_read2_b32 per pixel.
            unsigned int qA[4], qB[4], qC[4], qD[4];
#pragma unroll
            for (int k = 0; k < 4; ++k) {
                const int i0 = idx[it][k];
                qA[k] = W[i0];                       // (c000, c001)
                qB[k] = W[i0 + LUT_D];               // (c010, c011)
                qC[k] = W[i0 + LUT_DD];              // (c100, c101)
                qD[k] = W[i0 + LUT_DD + LUT_D];      // (c110, c111)
            }
            float oo[4];
#pragma unroll
            for (int k = 0; k < 4; ++k) {
                const float2 a00 = unpack2(qA[k]);
                const float2 a01 = unpack2(qB[k]);
                const float2 a10 = unpack2(qC[k]);
                const float2 a11 = unpack2(qD[k]);
                const float l00 = a00.x + dr[it][k] * (a00.y - a00.x);
                const float l01 = a01.x + dr[it][k] * (a01.y - a01.x);
                const float l10 = a10.x + dr[it][k] * (a10.y - a10.x);
                const float l11 = a11.x + dr[it][k] * (a11.y - a11.x);
                const float l0  = l00 + dg[it][k] * (l01 - l00);
                const float l1  = l10 + dg[it][k] * (l11 - l10);
                oo[k] = l0 + db[it][k] * (l1 - l0);
            }
            vfloat4 v = {oo[0], oo[1], oo[2], oo[3]};
            __builtin_nontemporal_store(v, (vfloat4*)&o4[ibase[it] + c * HW4]);
        }
    }
}

extern "C" void kernel_launch(void* const* d_in, const int* in_sizes, int n_in,
                              void* d_out, int out_size, void* d_ws, size_t ws_size,
                              hipStream_t stream) {
    const float* lut = (const float*)d_in[0];   // [3, 33, 33, 33]
    const float* x   = (const float*)d_in[1];   // [4, 3, 1024, 1024]
    float*       out = (float*)d_out;
    (void)d_ws; (void)ws_size;                  // workspace intentionally unused

    const size_t lds_bytes = (size_t)LUT_N * 4; // 143,748 B -> 1 block/CU
    lut3d_trilerp_kernel<<<NCHUNKS, THREADS, lds_bytes, stream>>>(lut, x, out);
}

// Round 3
// 112.155 us; speedup vs baseline: 1.1424x; 1.1424x over previous
//
#include <hip/hip_runtime.h>
#include <hip/hip_fp16.h>

// Trilinear 3D-LUT interpolation (image-adaptive-3DLUT forward).
// lut: [3, 33, 33, 33] fp32, x: [4, 3, 1024, 1024] fp32 in [0,1], out same as x.
//
// R6: R5's counters showed the merged kernel is a serial-phase latency kernel
// (all pipes <40%: VALU 18.5%, hbm 18%, conflicts 6.5us/CU; 50us ~= sum of
// non-overlapped phases). Keep single-generation + x-read-once, remove serial
// exposure:
//  - ws pre-pack kernel (R3) restored: channel staging is pure
//    global_load_lds DMA (no VALU pack chain, no VGPR roundtrip).
//  - Phase A x loads issued FIRST, channel-0 DMA issued while x in flight,
//    idx/deltas computed while both land; ONE barrier drains all.
//  - channel switch = barrier -> 9 DMA issues -> barrier (~1.3us exposed,
//    vs ~5us in-kernel pack phases in R5).
//  - gather stays fp16-pairs: 2x ds_read2_b32 per pixel (half the LDS traffic
//    of any non-duplicated layout).

#define LUT_D     33
#define LUT_DD    (LUT_D * LUT_D)            // 1089
#define LUT_N     (LUT_D * LUT_D * LUT_D)    // 35937
#define CH_STRIDE 35940                      // u32 per channel in ws, 16B-aligned
#define STAGE_G   (CH_STRIDE / 4)            // 8985 dwordx4 groups per channel
#define HW4       (1024 * 1024 / 4)          // 262144 float4 groups per plane
#define NGROUPS   (4 * HW4)                  // 1048576 groups per plane-set
#define NCHUNKS   256
#define THREADS   1024
#define ITERS     (NGROUPS / NCHUNKS / THREADS)  // 4

typedef float vfloat4 __attribute__((ext_vector_type(4)));

__device__ __forceinline__ unsigned int pack2(float a, float b) {
    union { __half2 h; unsigned int u; } cv;
    cv.h = __floats2half2_rn(a, b);
    return cv.u;
}
__device__ __forceinline__ float2 unpack2(unsigned int p) {
    union { unsigned int u; __half2 h; } cv;
    cv.u = p;
    return __half22float2(cv.h);
}

// ---- Pass 1: pack lut fp32 -> fp16-pair array ws[c*CH_STRIDE + i] = (v[i], v[i+1])
__global__ __launch_bounds__(256)
void lut_pack_kernel(const float* __restrict__ lut, unsigned int* __restrict__ W) {
    const int t = blockIdx.x * 256 + (int)threadIdx.x;
    if (t >= 3 * LUT_N) return;
    const int c = t / LUT_N;
    const int i = t - c * LUT_N;
    const float a = lut[t];
    const float b = (i + 1 < LUT_N) ? lut[t + 1] : 0.0f;
    W[c * CH_STRIDE + i] = pack2(a, b);
}

// ---- Pass 2: main interpolation, one block per chunk (1 block/CU), all 3
// channels per block, LDS re-staged per channel via async DMA.
__global__ __launch_bounds__(THREADS)
void lut3d_trilerp_kernel(const unsigned int* __restrict__ Wsrc,
                          const float* __restrict__ x,
                          float* __restrict__ out) {
    extern __shared__ __align__(16) unsigned int W[];  // CH_STRIDE u32 = 143,760 B

    const int t     = (int)threadIdx.x;
    const int chunk = blockIdx.x;                      // [0, 256)

    const float4* x4 = (const float4*)x;
    float4*       o4 = (float4*)out;
    const int g0 = chunk * (NGROUPS / NCHUNKS) + t;

    // ---- Phase A1: issue ALL x loads first (critical HBM latency+BW term).
    float4 R[ITERS], G[ITERS], B[ITERS];
    int ibase[ITERS];
#pragma unroll
    for (int it = 0; it < ITERS; ++it) {
        const int g     = g0 + it * THREADS;
        const int b_img = g >> 18;            // g / HW4  (HW4 = 2^18)
        const int hw4   = g & (HW4 - 1);
        ibase[it] = b_img * 3 * HW4 + hw4;
        R[it] = x4[ibase[it]];
        G[it] = x4[ibase[it] + HW4];
        B[it] = x4[ibase[it] + 2 * HW4];
    }

    // ---- Phase A2: DMA-stage channel 0 while x is in flight.
#pragma unroll
    for (int s = 0; s < 9; ++s) {
        const int gid = s * THREADS + t;
        if (gid < STAGE_G) {
            __builtin_amdgcn_global_load_lds(
                (const __attribute__((address_space(1))) void*)(Wsrc + gid * 4),
                (__attribute__((address_space(3))) void*)(W + gid * 4),
                16, 0, 0);
        }
    }

    // ---- Phase A3: idx + deltas, consuming x as it lands.
    int   idx[ITERS][4];
    float dr[ITERS][4], dg[ITERS][4], db[ITERS][4];
#pragma unroll
    for (int it = 0; it < ITERS; ++it) {
        const float rr[4] = {R[it].x, R[it].y, R[it].z, R[it].w};
        const float gg[4] = {G[it].x, G[it].y, G[it].z, G[it].w};
        const float bb[4] = {B[it].x, B[it].y, B[it].z, B[it].w};
#pragma unroll
        for (int k = 0; k < 4; ++k) {
            const float sr = rr[k] * 32.0f;
            const float sg = gg[k] * 32.0f;
            const float sb = bb[k] * 32.0f;
            const float fr = fminf(fmaxf(floorf(sr), 0.0f), 31.0f);
            const float fg = fminf(fmaxf(floorf(sg), 0.0f), 31.0f);
            const float fb = fminf(fmaxf(floorf(sb), 0.0f), 31.0f);
            dr[it][k] = sr - fr;
            dg[it][k] = sg - fg;
            db[it][k] = sb - fb;
            idx[it][k] = ((int)fb * LUT_D + (int)fg) * LUT_D + (int)fr;
        }
    }

    __syncthreads();   // drains x loads + DMA (vmcnt 0) before first gather

    // ---- Phase B: channels, gather/lerp/store; cheap DMA switch between.
#pragma unroll
    for (int c = 0; c < 3; ++c) {
#pragma unroll
        for (int it = 0; it < ITERS; ++it) {
            // 8 corners per pixel as 4 fp16-pairs -> 2 ds_read2_b32 per pixel.
            unsigned int qA[4], qB[4], qC[4], qD[4];
#pragma unroll
            for (int k = 0; k < 4; ++k) {
                const int i0 = idx[it][k];
                qA[k] = W[i0];                       // (c000, c001)
                qB[k] = W[i0 + LUT_D];               // (c010, c011)
                qC[k] = W[i0 + LUT_DD];              // (c100, c101)
                qD[k] = W[i0 + LUT_DD + LUT_D];      // (c110, c111)
            }
            float oo[4];
#pragma unroll
            for (int k = 0; k < 4; ++k) {
                const float2 a00 = unpack2(qA[k]);
                const float2 a01 = unpack2(qB[k]);
                const float2 a10 = unpack2(qC[k]);
                const float2 a11 = unpack2(qD[k]);
                const float l00 = a00.x + dr[it][k] * (a00.y - a00.x);
                const float l01 = a01.x + dr[it][k] * (a01.y - a01.x);
                const float l10 = a10.x + dr[it][k] * (a10.y - a10.x);
                const float l11 = a11.x + dr[it][k] * (a11.y - a11.x);
                const float l0  = l00 + dg[it][k] * (l01 - l00);
                const float l1  = l10 + dg[it][k] * (l11 - l10);
                oo[k] = l0 + db[it][k] * (l1 - l0);
            }
            vfloat4 v = {oo[0], oo[1], oo[2], oo[3]};
            __builtin_nontemporal_store(v, (vfloat4*)&o4[ibase[it] + c * HW4]);
        }

        if (c < 2) {
            __syncthreads();   // all gathers of channel c done before overwrite
            const unsigned int* src = Wsrc + (c + 1) * CH_STRIDE;
#pragma unroll
            for (int s = 0; s < 9; ++s) {
                const int gid = s * THREADS + t;
                if (gid < STAGE_G) {
                    __builtin_amdgcn_global_load_lds(
                        (const __attribute__((address_space(1))) void*)(src + gid * 4),
                        (__attribute__((address_space(3))) void*)(W + gid * 4),
                        16, 0, 0);
                }
            }
            __syncthreads();   // DMA drained (vmcnt 0) -> channel c+1 visible
        }
    }
}

extern "C" void kernel_launch(void* const* d_in, const int* in_sizes, int n_in,
                              void* d_out, int out_size, void* d_ws, size_t ws_size,
                              hipStream_t stream) {
    const float*  lut = (const float*)d_in[0];   // [3, 33, 33, 33]
    const float*  x   = (const float*)d_in[1];   // [4, 3, 1024, 1024]
    float*        out = (float*)d_out;
    unsigned int* W   = (unsigned int*)d_ws;     // 3*CH_STRIDE u32 = 431,280 B

    const int pack_grid = (3 * LUT_N + 255) / 256;   // 422
    lut_pack_kernel<<<pack_grid, 256, 0, stream>>>(lut, W);

    const size_t lds_bytes = (size_t)CH_STRIDE * 4;  // 143,760 B -> 1 block/CU
    lut3d_trilerp_kernel<<<NCHUNKS, THREADS, lds_bytes, stream>>>(W, x, out);
}